// Round 1
// 197.769 us; speedup vs baseline: 1.0128x; 1.0128x over previous
//
#include <hip/hip_runtime.h>

#define HIST_BINS 64
#define NBATCH 128
#define THREADS 256
#define BLOCKS_PER_BATCH 16
#define WAVES_PER_BLOCK (THREADS / 64)

// ---------------------------------------------------------------------------
// Kernel 1: per-batch 64-bin histogram of valid values in [0, 255].
// Grid: (BLOCKS_PER_BATCH, NBATCH). Per-wave LDS histograms; each block
// writes its PARTIAL histogram with plain stores (no global atomics, no
// pre-zeroing memset needed — poison is fully overwritten).
// 4 float4 loads batched per iteration to keep 4 VMEM ops in flight per wave.
// ---------------------------------------------------------------------------
__global__ __launch_bounds__(THREADS) void hist_kernel(
    const float* __restrict__ g, unsigned int* __restrict__ partial, int n_per_batch) {
    __shared__ unsigned int lh[WAVES_PER_BLOCK][HIST_BINS];

    const int tid  = threadIdx.x;
    const int wave = tid >> 6;

    // zero LDS histograms
    for (int i = tid; i < WAVES_PER_BLOCK * HIST_BINS; i += THREADS)
        ((unsigned int*)lh)[i] = 0u;
    __syncthreads();

    const int batch = blockIdx.y;
    const float4* gp = (const float4*)(g + (size_t)batch * (size_t)n_per_batch);
    const int n4 = n_per_batch >> 2;                    // float4 count per batch
    const float scale = 64.0f / 255.0f;                 // matches f32(64/255) in ref

    // val >= 0 ⇒ (int) truncation == floor; val <= 255 ⇒ idx <= 64, clamp high only.
#define PROC(v4)                                                        \
    {                                                                   \
        float vs[4] = {(v4).x, (v4).y, (v4).z, (v4).w};                 \
        _Pragma("unroll")                                               \
        for (int j = 0; j < 4; ++j) {                                   \
            float val = vs[j];                                          \
            if (val >= 0.0f && val <= 255.0f) {                         \
                unsigned int idx = (unsigned int)(int)(val * scale);    \
                if (idx > 63u) idx = 63u;                               \
                atomicAdd(&lh[wave][idx], 1u);                          \
            }                                                           \
        }                                                               \
    }

    const int stride = BLOCKS_PER_BATCH * THREADS;
    int i = blockIdx.x * THREADS + tid;
    // main loop: 4 independent float4 loads in flight per wave (16 KB/wave)
    for (; i + 3 * stride < n4; i += 4 * stride) {
        float4 a = gp[i];
        float4 b = gp[i + stride];
        float4 c = gp[i + 2 * stride];
        float4 d = gp[i + 3 * stride];
        PROC(a) PROC(b) PROC(c) PROC(d)
    }
    for (; i < n4; i += stride) {
        float4 a = gp[i];
        PROC(a)
    }
#undef PROC
    __syncthreads();

    // plain store of this block's partial histogram (overwrites ws poison)
    if (tid < HIST_BINS) {
        unsigned int s = 0;
#pragma unroll
        for (int w = 0; w < WAVES_PER_BLOCK; ++w) s += lh[w][tid];
        partial[((size_t)batch * BLOCKS_PER_BATCH + blockIdx.x) * HIST_BINS + tid] = s;
    }
}

// ---------------------------------------------------------------------------
// Kernel 2: sum the 16 block-partials, normalize (L1), then
// MLP: relu(hist @ W1^T + b1) @ W2^T + b2.  One block (128 threads) per batch.
// ---------------------------------------------------------------------------
__global__ __launch_bounds__(128) void mlp_kernel(
    const unsigned int* __restrict__ partial,
    const float* __restrict__ W1, const float* __restrict__ b1,
    const float* __restrict__ W2, const float* __restrict__ b2,
    float* __restrict__ out) {
    __shared__ float hn[HIST_BINS];
    __shared__ float h[32];

    const int b   = blockIdx.x;
    const int tid = threadIdx.x;

    if (tid < HIST_BINS) {
        unsigned int s = 0;
        const unsigned int* p = partial + (size_t)b * BLOCKS_PER_BATCH * HIST_BINS + tid;
#pragma unroll
        for (int w = 0; w < BLOCKS_PER_BATCH; ++w) s += p[w * HIST_BINS];
        hn[tid] = (float)s;
    }
    __syncthreads();

    // L1 sum: counts are integers <= 2^18, exact in fp32 regardless of order
    float sum = 0.0f;
    for (int i = 0; i < HIST_BINS; ++i) sum += hn[i];
    const float denom = fmaxf(sum, 1e-12f);
    __syncthreads();

    if (tid < HIST_BINS) hn[tid] = hn[tid] / denom;  // divide (match ref rounding)
    __syncthreads();

    if (tid < 32) {
        float acc = b1[tid];
        for (int k = 0; k < HIST_BINS; ++k) acc += hn[k] * W1[tid * HIST_BINS + k];
        h[tid] = fmaxf(acc, 0.0f);
    }
    __syncthreads();

    float acc = b2[tid];
    for (int k = 0; k < 32; ++k) acc += h[k] * W2[tid * 32 + k];
    out[b * 128 + tid] = acc;
}

extern "C" void kernel_launch(void* const* d_in, const int* in_sizes, int n_in,
                              void* d_out, int out_size, void* d_ws, size_t ws_size,
                              hipStream_t stream) {
    const float* g  = (const float*)d_in[0];
    const float* W1 = (const float*)d_in[1];
    const float* b1 = (const float*)d_in[2];
    const float* W2 = (const float*)d_in[3];
    const float* b2 = (const float*)d_in[4];
    float* out = (float*)d_out;

    unsigned int* partial = (unsigned int*)d_ws;    // 128*16*64*4 = 512 KB
    const int n_per_batch = in_sizes[0] / NBATCH;   // 512*512 = 262144

    // No memset: every partial[] slot is written by a plain store in hist_kernel,
    // so the 0xAA ws poison is fully overwritten. Two dispatches total.
    hist_kernel<<<dim3(BLOCKS_PER_BATCH, NBATCH), THREADS, 0, stream>>>(g, partial, n_per_batch);
    mlp_kernel<<<NBATCH, 128, 0, stream>>>(partial, W1, b1, W2, b2, out);
}

// Round 2
// 195.741 us; speedup vs baseline: 1.0233x; 1.0104x over previous
//
#include <hip/hip_runtime.h>

#define HIST_BINS 64
#define NBATCH 128
#define THREADS 256
#define BLOCKS_PER_BATCH 16
#define WAVES_PER_BLOCK (THREADS / 64)

// ---------------------------------------------------------------------------
// Kernel 1: per-batch 64-bin histogram of valid values in [0, 255].
// Grid: (BLOCKS_PER_BATCH, NBATCH). Per-wave LDS histograms; each block
// writes its PARTIAL histogram with plain stores (no global atomics, no
// memset — the 0xAA ws poison is fully overwritten).
// 8 float4 loads batched per iteration (statically indexed -> registers,
// not scratch) so each lane's 16 loads issue in two fully-pipelined bursts.
// ---------------------------------------------------------------------------
__global__ __launch_bounds__(THREADS) void hist_kernel(
    const float* __restrict__ g, unsigned int* __restrict__ partial, int n_per_batch) {
    __shared__ unsigned int lh[WAVES_PER_BLOCK][HIST_BINS];

    const int tid  = threadIdx.x;
    const int wave = tid >> 6;

    // zero LDS histograms
    for (int i = tid; i < WAVES_PER_BLOCK * HIST_BINS; i += THREADS)
        ((unsigned int*)lh)[i] = 0u;
    __syncthreads();

    const int batch = blockIdx.y;
    const float4* gp = (const float4*)(g + (size_t)batch * (size_t)n_per_batch);
    const int n4 = n_per_batch >> 2;                    // float4 count per batch
    const float scale = 64.0f / 255.0f;                 // matches f32(64/255) in ref

    // val >= 0 ⇒ (int) truncation == floor; val <= 255 ⇒ only high clamp needed.
#define PROC(v4)                                                        \
    {                                                                   \
        float vs[4] = {(v4).x, (v4).y, (v4).z, (v4).w};                 \
        _Pragma("unroll")                                               \
        for (int j = 0; j < 4; ++j) {                                   \
            float val = vs[j];                                          \
            if (val >= 0.0f && val <= 255.0f) {                         \
                unsigned int idx = (unsigned int)(int)(val * scale);    \
                idx = min(idx, 63u);                                    \
                atomicAdd(&lh[wave][idx], 1u);                          \
            }                                                           \
        }                                                               \
    }

    const int stride = BLOCKS_PER_BATCH * THREADS;
    int i = blockIdx.x * THREADS + tid;

    // main loop: 8 independent float4 loads in flight per lane (32 VGPRs of
    // data, all indices compile-time after unroll). For the bench shape each
    // lane owns exactly 16 float4s -> two iterations of this loop, no tail.
    for (; i + 7 * stride < n4; i += 8 * stride) {
        float4 v[8];
#pragma unroll
        for (int u = 0; u < 8; ++u) v[u] = gp[i + u * stride];
#pragma unroll
        for (int u = 0; u < 8; ++u) PROC(v[u])
    }
    for (; i < n4; i += stride) {
        float4 a = gp[i];
        PROC(a)
    }
#undef PROC
    __syncthreads();

    // plain store of this block's partial histogram (overwrites ws poison)
    if (tid < HIST_BINS) {
        unsigned int s = 0;
#pragma unroll
        for (int w = 0; w < WAVES_PER_BLOCK; ++w) s += lh[w][tid];
        partial[((size_t)batch * BLOCKS_PER_BATCH + blockIdx.x) * HIST_BINS + tid] = s;
    }
}

// ---------------------------------------------------------------------------
// Kernel 2: sum the 16 block-partials, normalize (L1), then
// MLP: relu(hist @ W1^T + b1) @ W2^T + b2.  One block (128 threads) per batch.
// ---------------------------------------------------------------------------
__global__ __launch_bounds__(128) void mlp_kernel(
    const unsigned int* __restrict__ partial,
    const float* __restrict__ W1, const float* __restrict__ b1,
    const float* __restrict__ W2, const float* __restrict__ b2,
    float* __restrict__ out) {
    __shared__ float hn[HIST_BINS];
    __shared__ float h[32];

    const int b   = blockIdx.x;
    const int tid = threadIdx.x;

    if (tid < HIST_BINS) {
        unsigned int s = 0;
        const unsigned int* p = partial + (size_t)b * BLOCKS_PER_BATCH * HIST_BINS + tid;
#pragma unroll
        for (int w = 0; w < BLOCKS_PER_BATCH; ++w) s += p[w * HIST_BINS];
        hn[tid] = (float)s;
    }
    __syncthreads();

    // L1 sum: counts are integers <= 2^18, exact in fp32 regardless of order
    float sum = 0.0f;
    for (int i = 0; i < HIST_BINS; ++i) sum += hn[i];
    const float denom = fmaxf(sum, 1e-12f);
    __syncthreads();

    if (tid < HIST_BINS) hn[tid] = hn[tid] / denom;  // divide (match ref rounding)
    __syncthreads();

    if (tid < 32) {
        float acc = b1[tid];
        for (int k = 0; k < HIST_BINS; ++k) acc += hn[k] * W1[tid * HIST_BINS + k];
        h[tid] = fmaxf(acc, 0.0f);
    }
    __syncthreads();

    float acc = b2[tid];
    for (int k = 0; k < 32; ++k) acc += h[k] * W2[tid * 32 + k];
    out[b * 128 + tid] = acc;
}

extern "C" void kernel_launch(void* const* d_in, const int* in_sizes, int n_in,
                              void* d_out, int out_size, void* d_ws, size_t ws_size,
                              hipStream_t stream) {
    const float* g  = (const float*)d_in[0];
    const float* W1 = (const float*)d_in[1];
    const float* b1 = (const float*)d_in[2];
    const float* W2 = (const float*)d_in[3];
    const float* b2 = (const float*)d_in[4];
    float* out = (float*)d_out;

    unsigned int* partial = (unsigned int*)d_ws;    // 128*16*64*4 = 512 KB
    const int n_per_batch = in_sizes[0] / NBATCH;   // 512*512 = 262144

    // No memset: every partial[] slot is written by a plain store in hist_kernel,
    // so the 0xAA ws poison is fully overwritten. Two dispatches total.
    hist_kernel<<<dim3(BLOCKS_PER_BATCH, NBATCH), THREADS, 0, stream>>>(g, partial, n_per_batch);
    mlp_kernel<<<NBATCH, 128, 0, stream>>>(partial, W1, b1, W2, b2, out);
}